// Round 2
// baseline (172.819 us; speedup 1.0000x reference)
//
#include <hip/hip_runtime.h>
#include <hip/hip_bf16.h>

typedef _Float16 half_t;
typedef half_t halfx8 __attribute__((ext_vector_type(8)));
typedef float f32x4 __attribute__((ext_vector_type(4)));

#define B_ 8
#define C_ 128
#define T_ 4096
#define H_ 64
#define L2E 1.44269504088896340736f

// ---------------------------------------------------------------------------
// Kernel 1: projections. theta/phi/g = W[64,128] @ x[b][128, t-tile(64)] + bias
// Outputs: Q [B,T,H] f16, K [B,T,H] f16, Vt [B,H,T] f16
// MFMA 16x16x32_f16: A = W chunk [16h x 32c], B = x chunk [32c x 16t]
// ---------------------------------------------------------------------------
__global__ __launch_bounds__(256) void proj_kernel(
    const float* __restrict__ x,
    const float* __restrict__ w_theta, const float* __restrict__ b_theta,
    const float* __restrict__ w_phi,   const float* __restrict__ b_phi,
    const float* __restrict__ w_g,     const float* __restrict__ b_g,
    half_t* __restrict__ Q, half_t* __restrict__ Ko, half_t* __restrict__ Vt)
{
    __shared__ __align__(16) half_t xt[64][136];   // [t][c]
    __shared__ __align__(16) half_t ts[64][72];    // transpose buf [t][h]

    const int tid  = threadIdx.x;
    const int lane = tid & 63;
    const int wave = tid >> 6;
    const int b    = blockIdx.x >> 6;
    const int t0   = (blockIdx.x & 63) << 6;

    const int rowA  = lane & 15;   // A-row / B-col / D-col index
    const int kgrp  = lane >> 4;   // k-group 0..3
    const int row_d = kgrp << 2;   // D-row base

    // ---- stage x[b][:, t0:t0+64] -> xt[t][c] (f32 -> f16, transposed) ----
    const float* xb = x + (size_t)b * C_ * T_ + t0;
    #pragma unroll
    for (int it = 0; it < 8; ++it) {
        int li = it * 256 + tid;        // 2048 float4 chunks: 128c x 16 tchunks
        int c  = li >> 4;
        int tc = li & 15;
        f32x4 v = *(const f32x4*)(xb + (size_t)c * T_ + tc * 4);
        #pragma unroll
        for (int j = 0; j < 4; ++j) xt[tc * 4 + j][c] = (half_t)v[j];
    }

    // ---- load W fragments (f32 global -> f16 regs), wave handles h0..h0+15 ----
    const int h0 = wave << 4;
    const float* Ws[3] = {w_theta, w_phi, w_g};
    const float* Bs[3] = {b_theta, b_phi, b_g};
    halfx8 wa[3][4];
    #pragma unroll
    for (int m = 0; m < 3; ++m) {
        const float* wrow = Ws[m] + (size_t)(h0 + rowA) * C_;
        #pragma unroll
        for (int cc = 0; cc < 4; ++cc) {
            const float* p = wrow + cc * 32 + kgrp * 8;
            f32x4 a = *(const f32x4*)p;
            f32x4 c2 = *(const f32x4*)(p + 4);
            halfx8 f;
            f[0]=(half_t)a[0]; f[1]=(half_t)a[1]; f[2]=(half_t)a[2]; f[3]=(half_t)a[3];
            f[4]=(half_t)c2[0];f[5]=(half_t)c2[1];f[6]=(half_t)c2[2];f[7]=(half_t)c2[3];
            wa[m][cc] = f;
        }
    }

    __syncthreads();

    #pragma unroll
    for (int m = 0; m < 3; ++m) {
        f32x4 acc[4] = {};   // 4 t-tiles of 16x16
        #pragma unroll
        for (int tt = 0; tt < 4; ++tt) {
            #pragma unroll
            for (int cc = 0; cc < 4; ++cc) {
                halfx8 bfrag = *(const halfx8*)&xt[tt * 16 + rowA][cc * 32 + kgrp * 8];
                acc[tt] = __builtin_amdgcn_mfma_f32_16x16x32_f16(wa[m][cc], bfrag, acc[tt], 0, 0, 0);
            }
        }
        float bias[4];
        #pragma unroll
        for (int r = 0; r < 4; ++r) bias[r] = Bs[m][h0 + row_d + r];

        if (m < 2) {
            // D: row=h_local, col=t_local. Write ts[t][h], transpose to [B,T,H].
            #pragma unroll
            for (int tt = 0; tt < 4; ++tt)
                #pragma unroll
                for (int r = 0; r < 4; ++r)
                    ts[tt * 16 + rowA][h0 + row_d + r] = (half_t)(acc[tt][r] + bias[r]);
            __syncthreads();
            half_t* dst = (m == 0 ? Q : Ko) + ((size_t)b * T_ + t0) * H_;
            #pragma unroll
            for (int it = 0; it < 2; ++it) {
                int q = it * 256 + tid;   // 512 16B chunks: 64t x 8
                int t = q >> 3, hc = q & 7;
                *(halfx8*)(dst + (size_t)t * H_ + hc * 8) = *(const halfx8*)&ts[t][hc * 8];
            }
            __syncthreads();
        } else {
            // g: write straight to Vt[b][h][t0+t] ([h][t] matches D layout)
            half_t* dst = Vt + (size_t)b * H_ * T_ + t0;
            #pragma unroll
            for (int tt = 0; tt < 4; ++tt)
                #pragma unroll
                for (int r = 0; r < 4; ++r)
                    dst[(size_t)(h0 + row_d + r) * T_ + tt * 16 + rowA] = (half_t)(acc[tt][r] + bias[r]);
        }
    }
}

// ---------------------------------------------------------------------------
// Kernel 2: flash attention. Per block: batch b, 64 Q-rows (16 per wave).
// KV loop over 64-row tiles. S = Q·K^T (f32 acc), online softmax, O += P·V.
// ---------------------------------------------------------------------------
__global__ __launch_bounds__(256) void attn_kernel(
    const half_t* __restrict__ Q, const half_t* __restrict__ K,
    const half_t* __restrict__ Vt, half_t* __restrict__ O)
{
    __shared__ __align__(16) half_t Kt[64][72];      // [s][h]
    __shared__ __align__(16) half_t Vl[64][72];      // [d][s]
    __shared__ __align__(16) half_t Pl[4][16][72];   // per-wave [t][s]

    const int tid  = threadIdx.x;
    const int lane = tid & 63;
    const int wave = tid >> 6;
    const int b    = blockIdx.x >> 6;
    const int t0   = (blockIdx.x & 63) << 6;

    const int rowA  = lane & 15;
    const int kgrp  = lane >> 4;
    const int row_d = kgrp << 2;

    // Q fragments for this wave's 16 rows (held in regs all loop long)
    const half_t* qrow = Q + ((size_t)b * T_ + t0 + wave * 16 + rowA) * H_;
    halfx8 qf[2];
    qf[0] = *(const halfx8*)(qrow + kgrp * 8);
    qf[1] = *(const halfx8*)(qrow + 32 + kgrp * 8);

    f32x4 oacc[4] = {};
    float mrow[4], lrow[4];
    #pragma unroll
    for (int r = 0; r < 4; ++r) { mrow[r] = -INFINITY; lrow[r] = 0.f; }

    const half_t* Kb = K  + (size_t)b * T_ * H_;
    const half_t* Vb = Vt + (size_t)b * H_ * T_;

    for (int s0 = 0; s0 < T_; s0 += 64) {
        __syncthreads();
        // stage K tile [s][h] and V tile [d][s] (both rows 128B contiguous)
        #pragma unroll
        for (int it = 0; it < 2; ++it) {
            int q = it * 256 + tid;
            int r = q >> 3, hc = q & 7;
            *(halfx8*)&Kt[r][hc * 8] = *(const halfx8*)(Kb + (size_t)(s0 + r) * H_ + hc * 8);
        }
        #pragma unroll
        for (int it = 0; it < 2; ++it) {
            int q = it * 256 + tid;
            int d = q >> 3, sc = q & 7;
            *(halfx8*)&Vl[d][sc * 8] = *(const halfx8*)(Vb + (size_t)d * T_ + s0 + sc * 8);
        }
        __syncthreads();

        // S = Q K^T : 4 s-tiles x (K=64 -> 2 chunks)
        f32x4 sacc[4] = {};
        #pragma unroll
        for (int st = 0; st < 4; ++st) {
            #pragma unroll
            for (int hc = 0; hc < 2; ++hc) {
                halfx8 kf = *(const halfx8*)&Kt[st * 16 + rowA][hc * 32 + kgrp * 8];
                sacc[st] = __builtin_amdgcn_mfma_f32_16x16x32_f16(qf[hc], kf, sacc[st], 0, 0, 0);
            }
        }

        // online softmax; this lane owns rows row_d+r (cols rowA across st-tiles)
        #pragma unroll
        for (int r = 0; r < 4; ++r) {
            float mt = fmaxf(fmaxf(sacc[0][r], sacc[1][r]), fmaxf(sacc[2][r], sacc[3][r]));
            #pragma unroll
            for (int off = 1; off < 16; off <<= 1)
                mt = fmaxf(mt, __shfl_xor(mt, off));
            float mnew  = fmaxf(mrow[r], mt);
            float scale = exp2f((mrow[r] - mnew) * L2E);
            mrow[r] = mnew;
            float psum = 0.f;
            #pragma unroll
            for (int st = 0; st < 4; ++st) {
                float p = exp2f((sacc[st][r] - mnew) * L2E);
                sacc[st][r] = p;
                psum += p;
            }
            #pragma unroll
            for (int off = 1; off < 16; off <<= 1)
                psum += __shfl_xor(psum, off);
            lrow[r] = lrow[r] * scale + psum;
            #pragma unroll
            for (int dt = 0; dt < 4; ++dt) oacc[dt][r] *= scale;
            #pragma unroll
            for (int st = 0; st < 4; ++st)
                Pl[wave][row_d + r][st * 16 + rowA] = (half_t)sacc[st][r];
        }

        // O += P V : A = Pl [t][s-chunk], B = Vl [s][d] (wave-private Pl)
        #pragma unroll
        for (int sc = 0; sc < 2; ++sc) {
            halfx8 pf = *(const halfx8*)&Pl[wave][rowA][sc * 32 + kgrp * 8];
            #pragma unroll
            for (int dt = 0; dt < 4; ++dt) {
                halfx8 vf = *(const halfx8*)&Vl[dt * 16 + rowA][sc * 32 + kgrp * 8];
                oacc[dt] = __builtin_amdgcn_mfma_f32_16x16x32_f16(pf, vf, oacc[dt], 0, 0, 0);
            }
        }
    }

    // normalize + write O [B,T,H] f16
    float inv[4];
    #pragma unroll
    for (int r = 0; r < 4; ++r) inv[r] = 1.f / lrow[r];
    half_t* orow = O + ((size_t)b * T_ + t0 + wave * 16) * H_;
    #pragma unroll
    for (int dt = 0; dt < 4; ++dt)
        #pragma unroll
        for (int r = 0; r < 4; ++r)
            orow[(size_t)(row_d + r) * H_ + dt * 16 + rowA] = (half_t)(oacc[dt][r] * inv[r]);
}

// ---------------------------------------------------------------------------
// Kernel 3: out = x + b_out + w_out[128,64] @ O^T ; MFMA with A=w_out, B=O[t][h]
// ---------------------------------------------------------------------------
__global__ __launch_bounds__(256) void outproj_kernel(
    const half_t* __restrict__ O, const float* __restrict__ w_out,
    const float* __restrict__ b_out, const float* __restrict__ x,
    float* __restrict__ out)
{
    __shared__ __align__(16) half_t Ot[64][72];   // [t][h]

    const int tid  = threadIdx.x;
    const int lane = tid & 63;
    const int wave = tid >> 6;
    const int b    = blockIdx.x >> 6;
    const int t0   = (blockIdx.x & 63) << 6;

    const int rowA  = lane & 15;
    const int kgrp  = lane >> 4;
    const int row_d = kgrp << 2;

    #pragma unroll
    for (int it = 0; it < 2; ++it) {
        int q = it * 256 + tid;
        int t = q >> 3, hc = q & 7;
        *(halfx8*)&Ot[t][hc * 8] = *(const halfx8*)(O + ((size_t)b * T_ + t0 + t) * H_ + hc * 8);
    }

    // wave's c-strip: 32 channels
    const int c0 = wave * 32;
    halfx8 wf[2][2];
    #pragma unroll
    for (int ct = 0; ct < 2; ++ct) {
        const float* wrow = w_out + (size_t)(c0 + ct * 16 + rowA) * H_;
        #pragma unroll
        for (int hc = 0; hc < 2; ++hc) {
            const float* p = wrow + hc * 32 + kgrp * 8;
            f32x4 a = *(const f32x4*)p;
            f32x4 c2 = *(const f32x4*)(p + 4);
            halfx8 f;
            f[0]=(half_t)a[0]; f[1]=(half_t)a[1]; f[2]=(half_t)a[2]; f[3]=(half_t)a[3];
            f[4]=(half_t)c2[0];f[5]=(half_t)c2[1];f[6]=(half_t)c2[2];f[7]=(half_t)c2[3];
            wf[ct][hc] = f;
        }
    }

    __syncthreads();

    #pragma unroll
    for (int ct = 0; ct < 2; ++ct) {
        #pragma unroll
        for (int tt = 0; tt < 4; ++tt) {
            f32x4 acc = {};
            #pragma unroll
            for (int hc = 0; hc < 2; ++hc) {
                halfx8 of = *(const halfx8*)&Ot[tt * 16 + rowA][hc * 32 + kgrp * 8];
                acc = __builtin_amdgcn_mfma_f32_16x16x32_f16(wf[ct][hc], of, acc, 0, 0, 0);
            }
            const int c = c0 + ct * 16 + row_d;
            const size_t base = (size_t)b * C_ * T_ + t0 + tt * 16 + rowA;
            #pragma unroll
            for (int r = 0; r < 4; ++r) {
                size_t idx = base + (size_t)(c + r) * T_;
                out[idx] = x[idx] + b_out[c + r] + acc[r];
            }
        }
    }
}

// ---------------------------------------------------------------------------
extern "C" void kernel_launch(void* const* d_in, const int* in_sizes, int n_in,
                              void* d_out, int out_size, void* d_ws, size_t ws_size,
                              hipStream_t stream) {
    const float* x       = (const float*)d_in[0];
    const float* w_theta = (const float*)d_in[1];
    const float* b_theta = (const float*)d_in[2];
    const float* w_phi   = (const float*)d_in[3];
    const float* b_phi   = (const float*)d_in[4];
    const float* w_g     = (const float*)d_in[5];
    const float* b_g     = (const float*)d_in[6];
    const float* w_out   = (const float*)d_in[7];
    const float* b_out   = (const float*)d_in[8];
    float* out = (float*)d_out;

    const size_t mat = (size_t)B_ * T_ * H_;   // 2 M elements
    half_t* Qw = (half_t*)d_ws;
    half_t* Kw = Qw + mat;
    half_t* Vw = Kw + mat;
    half_t* Ow = Vw + mat;                     // total 16 MB of ws

    dim3 grid(B_ * (T_ / 64)), block(256);
    proj_kernel<<<grid, block, 0, stream>>>(x, w_theta, b_theta, w_phi, b_phi,
                                            w_g, b_g, Qw, Kw, Vw);
    attn_kernel<<<grid, block, 0, stream>>>(Qw, Kw, Vw, Ow);
    outproj_kernel<<<grid, block, 0, stream>>>(Ow, w_out, b_out, x, out);
}

// Round 4
// 129.693 us; speedup vs baseline: 1.3325x; 1.3325x over previous
//
#include <hip/hip_runtime.h>
#include <hip/hip_bf16.h>

typedef _Float16 half_t;
typedef half_t halfx8 __attribute__((ext_vector_type(8)));
typedef half_t halfx4 __attribute__((ext_vector_type(4)));
typedef half_t halfx2 __attribute__((ext_vector_type(2)));
typedef __fp16 fp16x2 __attribute__((ext_vector_type(2)));
typedef float f32x4 __attribute__((ext_vector_type(4)));

#define B_ 8
#define C_ 128
#define T_ 4096
#define H_ 64
#define L2E 1.44269504088896340736f

static __device__ __forceinline__ halfx2 pk2(float a, float b) {
    fp16x2 r = __builtin_amdgcn_cvt_pkrtz(a, b);
    return __builtin_bit_cast(halfx2, r);
}

// ---------------------------------------------------------------------------
// Kernel 1: projections. theta/phi/g = W[64,128] @ x[b][128, t-tile(64)] + bias
// Q (theta, pre-scaled by log2e) [B,T,H], K (phi) [B,T,H], Vt (g) [B,H,T], f16
// ---------------------------------------------------------------------------
__global__ __launch_bounds__(256) void proj_kernel(
    const float* __restrict__ x,
    const float* __restrict__ w_theta, const float* __restrict__ b_theta,
    const float* __restrict__ w_phi,   const float* __restrict__ b_phi,
    const float* __restrict__ w_g,     const float* __restrict__ b_g,
    half_t* __restrict__ Q, half_t* __restrict__ Ko, half_t* __restrict__ Vt)
{
    __shared__ __align__(16) half_t xt[64][136];   // [t][c]
    __shared__ __align__(16) half_t ts[64][72];    // transpose buf [t][h]

    const int tid  = threadIdx.x;
    const int lane = tid & 63;
    const int wave = tid >> 6;
    const int b    = blockIdx.x >> 6;
    const int t0   = (blockIdx.x & 63) << 6;

    const int rowA  = lane & 15;
    const int kgrp  = lane >> 4;
    const int row_d = kgrp << 2;

    // stage x[b][:, t0:t0+64] -> xt[t][c] (f32 -> f16, transposed)
    const float* xb = x + (size_t)b * C_ * T_ + t0;
    #pragma unroll
    for (int it = 0; it < 8; ++it) {
        int li = it * 256 + tid;
        int c  = li >> 4;
        int tc = li & 15;
        f32x4 v = *(const f32x4*)(xb + (size_t)c * T_ + tc * 4);
        #pragma unroll
        for (int j = 0; j < 4; ++j) xt[tc * 4 + j][c] = (half_t)v[j];
    }

    const int h0 = wave << 4;
    const float* Ws[3] = {w_theta, w_phi, w_g};
    const float* Bs[3] = {b_theta, b_phi, b_g};
    halfx8 wa[3][4];
    #pragma unroll
    for (int m = 0; m < 3; ++m) {
        const float* wrow = Ws[m] + (size_t)(h0 + rowA) * C_;
        #pragma unroll
        for (int cc = 0; cc < 4; ++cc) {
            const float* p = wrow + cc * 32 + kgrp * 8;
            f32x4 a = *(const f32x4*)p;
            f32x4 c2 = *(const f32x4*)(p + 4);
            halfx8 f;
            f[0]=(half_t)a[0]; f[1]=(half_t)a[1]; f[2]=(half_t)a[2]; f[3]=(half_t)a[3];
            f[4]=(half_t)c2[0];f[5]=(half_t)c2[1];f[6]=(half_t)c2[2];f[7]=(half_t)c2[3];
            wa[m][cc] = f;
        }
    }

    __syncthreads();

    #pragma unroll
    for (int m = 0; m < 3; ++m) {
        f32x4 acc[4] = {};
        #pragma unroll
        for (int tt = 0; tt < 4; ++tt) {
            #pragma unroll
            for (int cc = 0; cc < 4; ++cc) {
                halfx8 bfrag = *(const halfx8*)&xt[tt * 16 + rowA][cc * 32 + kgrp * 8];
                acc[tt] = __builtin_amdgcn_mfma_f32_16x16x32_f16(wa[m][cc], bfrag, acc[tt], 0, 0, 0);
            }
        }
        float bias[4];
        #pragma unroll
        for (int r = 0; r < 4; ++r) bias[r] = Bs[m][h0 + row_d + r];

        if (m < 2) {
            const float sc = (m == 0) ? L2E : 1.0f;   // fold log2e into theta
            #pragma unroll
            for (int tt = 0; tt < 4; ++tt)
                #pragma unroll
                for (int r = 0; r < 4; ++r)
                    ts[tt * 16 + rowA][h0 + row_d + r] = (half_t)((acc[tt][r] + bias[r]) * sc);
            __syncthreads();
            half_t* dst = (m == 0 ? Q : Ko) + ((size_t)b * T_ + t0) * H_;
            #pragma unroll
            for (int it = 0; it < 2; ++it) {
                int q = it * 256 + tid;
                int t = q >> 3, hc = q & 7;
                *(halfx8*)(dst + (size_t)t * H_ + hc * 8) = *(const halfx8*)&ts[t][hc * 8];
            }
            __syncthreads();
        } else {
            half_t* dst = Vt + (size_t)b * H_ * T_ + t0;
            #pragma unroll
            for (int tt = 0; tt < 4; ++tt)
                #pragma unroll
                for (int r = 0; r < 4; ++r)
                    dst[(size_t)(h0 + row_d + r) * T_ + tt * 16 + rowA] = (half_t)(acc[tt][r] + bias[r]);
        }
    }
}

// ---------------------------------------------------------------------------
// Kernel 2: flash attention, swapped-operand form.
// Block: 4 waves x 32 q-rows = 128 q-rows; grid = B * T/128 = 256 (1 block/CU).
// Per KV tile (64 s): St = mfma(K_frag, Q_frag) -> lane owns one q-col,
// 16 s-values  => in-register softmax (2 shuffles). P packed via cvt_pkrtz,
// vectorized wave-private LDS round-trip feeds PV as O^T = mfma(V^T, P^T).
// K/V double-buffered in LDS with register prefetch (one barrier per tile).
// ---------------------------------------------------------------------------
__global__ __launch_bounds__(256) void attn_kernel(
    const half_t* __restrict__ Q, const half_t* __restrict__ K,
    const half_t* __restrict__ Vt, half_t* __restrict__ O)
{
    __shared__ __align__(16) half_t Kt[2][64][72];      // [buf][s][h]
    __shared__ __align__(16) half_t Vl[2][64][72];      // [buf][d][s]
    __shared__ __align__(16) half_t Pl[4][2][16][72];   // [wave][qa][q][s]

    const int tid  = threadIdx.x;
    const int lane = tid & 63;
    const int wave = tid >> 6;
    const int b    = blockIdx.x >> 5;
    const int t0   = (blockIdx.x & 31) << 7;   // 128 q-rows per block
    const int rowA = lane & 15;
    const int kgrp = lane >> 4;

    const int q0 = t0 + wave * 32;

    // Q fragments for both 16-row subtiles (B-operand layout == A layout)
    halfx8 qf[2][2];
    #pragma unroll
    for (int qa = 0; qa < 2; ++qa) {
        const half_t* qr = Q + ((size_t)b * T_ + q0 + qa * 16 + rowA) * H_ + kgrp * 8;
        qf[qa][0] = *(const halfx8*)qr;
        qf[qa][1] = *(const halfx8*)(qr + 32);
    }

    f32x4 oacc[2][4] = {};                   // [qa][dt] : O^T[d][q]
    float mr[2] = {-INFINITY, -INFINITY};
    float lr[2] = {0.f, 0.f};

    // staging: each thread owns 2 x 16B chunks of K and of V per tile
    const int r0 = tid >> 3;     // 0..31 (+32 for second chunk)
    const int c8 = (tid & 7) * 8;
    const half_t* kp = K  + (size_t)b * T_ * H_ + (size_t)r0 * H_ + c8;
    const half_t* vp = Vt + (size_t)b * H_ * T_ + (size_t)r0 * T_ + c8;

    halfx8 rK0, rK1, rV0, rV1;
    rK0 = *(const halfx8*)(kp);
    rK1 = *(const halfx8*)(kp + 32 * H_);
    rV0 = *(const halfx8*)(vp);
    rV1 = *(const halfx8*)(vp + 32 * T_);
    kp += 64 * H_; vp += 64;

    *(halfx8*)&Kt[0][r0][c8]      = rK0;
    *(halfx8*)&Kt[0][r0 + 32][c8] = rK1;
    *(halfx8*)&Vl[0][r0][c8]      = rV0;
    *(halfx8*)&Vl[0][r0 + 32][c8] = rV1;
    __syncthreads();

    for (int t = 0; t < T_ / 64; ++t) {
        const int cur = t & 1;
        const bool more = (t + 1 < T_ / 64);
        if (more) {   // issue next-tile loads; land under compute
            rK0 = *(const halfx8*)(kp);
            rK1 = *(const halfx8*)(kp + 32 * H_);
            rV0 = *(const halfx8*)(vp);
            rV1 = *(const halfx8*)(vp + 32 * T_);
            kp += 64 * H_; vp += 64;
        }

        // ---- St = K_tile . Q^T  (D: col=q, row=s) ----
        f32x4 sacc[2][4] = {};
        #pragma unroll
        for (int st = 0; st < 4; ++st) {
            #pragma unroll
            for (int hc = 0; hc < 2; ++hc) {
                halfx8 kf = *(const halfx8*)&Kt[cur][st * 16 + rowA][hc * 32 + kgrp * 8];
                sacc[0][st] = __builtin_amdgcn_mfma_f32_16x16x32_f16(kf, qf[0][hc], sacc[0][st], 0, 0, 0);
                sacc[1][st] = __builtin_amdgcn_mfma_f32_16x16x32_f16(kf, qf[1][hc], sacc[1][st], 0, 0, 0);
            }
        }

        // ---- in-register online softmax (scores already in log2 domain) ----
        #pragma unroll
        for (int qa = 0; qa < 2; ++qa) {
            float pm = sacc[qa][0][0];
            #pragma unroll
            for (int st = 0; st < 4; ++st)
                #pragma unroll
                for (int r = 0; r < 4; ++r)
                    pm = fmaxf(pm, sacc[qa][st][r]);
            pm = fmaxf(pm, __shfl_xor(pm, 16));
            pm = fmaxf(pm, __shfl_xor(pm, 32));
            float mnew  = fmaxf(mr[qa], pm);
            float scale = exp2f(mr[qa] - mnew);
            mr[qa] = mnew;
            f32x4 ps4 = {0.f, 0.f, 0.f, 0.f};
            #pragma unroll
            for (int st = 0; st < 4; ++st) {
                #pragma unroll
                for (int r = 0; r < 4; ++r)
                    sacc[qa][st][r] = exp2f(sacc[qa][st][r] - mnew);
                ps4 += sacc[qa][st];
            }
            float ps = (ps4[0] + ps4[1]) + (ps4[2] + ps4[3]);
            ps += __shfl_xor(ps, 16);
            ps += __shfl_xor(ps, 32);
            lr[qa] = lr[qa] * scale + ps;
            #pragma unroll
            for (int dt = 0; dt < 4; ++dt) oacc[qa][dt] *= scale;
            // pack P^T and write wave-private (vectorized 8B, q-major)
            #pragma unroll
            for (int st = 0; st < 4; ++st) {
                union { halfx2 h2[2]; halfx4 h4; } u;
                u.h2[0] = pk2(sacc[qa][st][0], sacc[qa][st][1]);
                u.h2[1] = pk2(sacc[qa][st][2], sacc[qa][st][3]);
                *(halfx4*)&Pl[wave][qa][rowA][st * 16 + kgrp * 4] = u.h4;
            }
        }

        // ---- O^T += V^T . P^T ----
        #pragma unroll
        for (int sc2 = 0; sc2 < 2; ++sc2) {
            halfx8 pf0 = *(const halfx8*)&Pl[wave][0][rowA][sc2 * 32 + kgrp * 8];
            halfx8 pf1 = *(const halfx8*)&Pl[wave][1][rowA][sc2 * 32 + kgrp * 8];
            #pragma unroll
            for (int dt = 0; dt < 4; ++dt) {
                halfx8 vf = *(const halfx8*)&Vl[cur][dt * 16 + rowA][sc2 * 32 + kgrp * 8];
                oacc[0][dt] = __builtin_amdgcn_mfma_f32_16x16x32_f16(vf, pf0, oacc[0][dt], 0, 0, 0);
                oacc[1][dt] = __builtin_amdgcn_mfma_f32_16x16x32_f16(vf, pf1, oacc[1][dt], 0, 0, 0);
            }
        }

        if (more) {   // write next tile into other buffer; single barrier
            const int nxt = cur ^ 1;
            *(halfx8*)&Kt[nxt][r0][c8]      = rK0;
            *(halfx8*)&Kt[nxt][r0 + 32][c8] = rK1;
            *(halfx8*)&Vl[nxt][r0][c8]      = rV0;
            *(halfx8*)&Vl[nxt][r0 + 32][c8] = rV1;
            __syncthreads();
        }
    }

    // ---- normalize + write O [B,T,H] (8B packed stores) ----
    #pragma unroll
    for (int qa = 0; qa < 2; ++qa) {
        float inv = 1.f / lr[qa];
        half_t* orow = O + ((size_t)b * T_ + q0 + qa * 16 + rowA) * H_;
        #pragma unroll
        for (int dt = 0; dt < 4; ++dt) {
            union { halfx2 h2[2]; halfx4 h4; } u;
            u.h2[0] = pk2(oacc[qa][dt][0] * inv, oacc[qa][dt][1] * inv);
            u.h2[1] = pk2(oacc[qa][dt][2] * inv, oacc[qa][dt][3] * inv);
            *(halfx4*)(orow + dt * 16 + kgrp * 4) = u.h4;
        }
    }
}

// ---------------------------------------------------------------------------
// Kernel 3: out = x + b_out + w_out[128,64] @ O^T
// ---------------------------------------------------------------------------
__global__ __launch_bounds__(256) void outproj_kernel(
    const half_t* __restrict__ O, const float* __restrict__ w_out,
    const float* __restrict__ b_out, const float* __restrict__ x,
    float* __restrict__ out)
{
    __shared__ __align__(16) half_t Ot[64][72];   // [t][h]

    const int tid  = threadIdx.x;
    const int lane = tid & 63;
    const int wave = tid >> 6;
    const int b    = blockIdx.x >> 6;
    const int t0   = (blockIdx.x & 63) << 6;

    const int rowA  = lane & 15;
    const int kgrp  = lane >> 4;
    const int row_d = kgrp << 2;

    #pragma unroll
    for (int it = 0; it < 2; ++it) {
        int q = it * 256 + tid;
        int t = q >> 3, hc = q & 7;
        *(halfx8*)&Ot[t][hc * 8] = *(const halfx8*)(O + ((size_t)b * T_ + t0 + t) * H_ + hc * 8);
    }

    const int c0 = wave * 32;
    halfx8 wf[2][2];
    #pragma unroll
    for (int ct = 0; ct < 2; ++ct) {
        const float* wrow = w_out + (size_t)(c0 + ct * 16 + rowA) * H_;
        #pragma unroll
        for (int hc = 0; hc < 2; ++hc) {
            const float* p = wrow + hc * 32 + kgrp * 8;
            f32x4 a = *(const f32x4*)p;
            f32x4 c2 = *(const f32x4*)(p + 4);
            halfx8 f;
            f[0]=(half_t)a[0]; f[1]=(half_t)a[1]; f[2]=(half_t)a[2]; f[3]=(half_t)a[3];
            f[4]=(half_t)c2[0];f[5]=(half_t)c2[1];f[6]=(half_t)c2[2];f[7]=(half_t)c2[3];
            wf[ct][hc] = f;
        }
    }

    __syncthreads();

    #pragma unroll
    for (int ct = 0; ct < 2; ++ct) {
        #pragma unroll
        for (int tt = 0; tt < 4; ++tt) {
            f32x4 acc = {};
            #pragma unroll
            for (int hc = 0; hc < 2; ++hc) {
                halfx8 of = *(const halfx8*)&Ot[tt * 16 + rowA][hc * 32 + kgrp * 8];
                acc = __builtin_amdgcn_mfma_f32_16x16x32_f16(wf[ct][hc], of, acc, 0, 0, 0);
            }
            const int c = c0 + ct * 16 + row_d;
            const size_t base = (size_t)b * C_ * T_ + t0 + tt * 16 + rowA;
            #pragma unroll
            for (int r = 0; r < 4; ++r) {
                size_t idx = base + (size_t)(c + r) * T_;
                out[idx] = x[idx] + b_out[c + r] + acc[r];
            }
        }
    }
}

// ---------------------------------------------------------------------------
extern "C" void kernel_launch(void* const* d_in, const int* in_sizes, int n_in,
                              void* d_out, int out_size, void* d_ws, size_t ws_size,
                              hipStream_t stream) {
    const float* x       = (const float*)d_in[0];
    const float* w_theta = (const float*)d_in[1];
    const float* b_theta = (const float*)d_in[2];
    const float* w_phi   = (const float*)d_in[3];
    const float* b_phi   = (const float*)d_in[4];
    const float* w_g     = (const float*)d_in[5];
    const float* b_g     = (const float*)d_in[6];
    const float* w_out   = (const float*)d_in[7];
    const float* b_out   = (const float*)d_in[8];
    float* out = (float*)d_out;

    const size_t mat = (size_t)B_ * T_ * H_;   // 2 M elements
    half_t* Qw = (half_t*)d_ws;
    half_t* Kw = Qw + mat;
    half_t* Vw = Kw + mat;
    half_t* Ow = Vw + mat;                     // 16 MB of ws total

    proj_kernel<<<dim3(B_ * (T_ / 64)), dim3(256), 0, stream>>>(
        x, w_theta, b_theta, w_phi, b_phi, w_g, b_g, Qw, Kw, Vw);
    attn_kernel<<<dim3(B_ * (T_ / 128)), dim3(256), 0, stream>>>(Qw, Kw, Vw, Ow);
    outproj_kernel<<<dim3(B_ * (T_ / 64)), dim3(256), 0, stream>>>(Ow, w_out, b_out, x, out);
}

// Round 5
// 111.606 us; speedup vs baseline: 1.5485x; 1.1621x over previous
//
#include <hip/hip_runtime.h>
#include <hip/hip_bf16.h>

typedef _Float16 half_t;
typedef half_t halfx8 __attribute__((ext_vector_type(8)));
typedef half_t halfx4 __attribute__((ext_vector_type(4)));
typedef half_t halfx2 __attribute__((ext_vector_type(2)));
typedef __fp16 fp16x2 __attribute__((ext_vector_type(2)));
typedef float f32x4 __attribute__((ext_vector_type(4)));

#define B_ 8
#define C_ 128
#define T_ 4096
#define H_ 64
#define L2E 1.44269504088896340736f

static __device__ __forceinline__ halfx2 pk2(float a, float b) {
    fp16x2 r = __builtin_amdgcn_cvt_pkrtz(a, b);
    return __builtin_bit_cast(halfx2, r);
}

// ---------------------------------------------------------------------------
// Kernel 1: projections. theta/phi/g = W[64,128] @ x[b][128, t-tile(64)] + bias
// Q (theta, pre-scaled by log2e) [B,T,H], K (phi) [B,T,H], Vt (g) [B,H,T], f16
// ---------------------------------------------------------------------------
__global__ __launch_bounds__(256) void proj_kernel(
    const float* __restrict__ x,
    const float* __restrict__ w_theta, const float* __restrict__ b_theta,
    const float* __restrict__ w_phi,   const float* __restrict__ b_phi,
    const float* __restrict__ w_g,     const float* __restrict__ b_g,
    half_t* __restrict__ Q, half_t* __restrict__ Ko, half_t* __restrict__ Vt)
{
    __shared__ __align__(16) half_t xt[64][136];   // [t][c]
    __shared__ __align__(16) half_t ts[64][72];    // transpose buf [t][h]

    const int tid  = threadIdx.x;
    const int lane = tid & 63;
    const int wave = tid >> 6;
    const int b    = blockIdx.x >> 6;
    const int t0   = (blockIdx.x & 63) << 6;

    const int rowA  = lane & 15;
    const int kgrp  = lane >> 4;
    const int row_d = kgrp << 2;

    // stage x[b][:, t0:t0+64] -> xt[t][c] (f32 -> f16, transposed)
    const float* xb = x + (size_t)b * C_ * T_ + t0;
    #pragma unroll
    for (int it = 0; it < 8; ++it) {
        int li = it * 256 + tid;
        int c  = li >> 4;
        int tc = li & 15;
        f32x4 v = *(const f32x4*)(xb + (size_t)c * T_ + tc * 4);
        #pragma unroll
        for (int j = 0; j < 4; ++j) xt[tc * 4 + j][c] = (half_t)v[j];
    }

    const int h0 = wave << 4;
    const float* Ws[3] = {w_theta, w_phi, w_g};
    const float* Bs[3] = {b_theta, b_phi, b_g};
    halfx8 wa[3][4];
    #pragma unroll
    for (int m = 0; m < 3; ++m) {
        const float* wrow = Ws[m] + (size_t)(h0 + rowA) * C_;
        #pragma unroll
        for (int cc = 0; cc < 4; ++cc) {
            const float* p = wrow + cc * 32 + kgrp * 8;
            f32x4 a = *(const f32x4*)p;
            f32x4 c2 = *(const f32x4*)(p + 4);
            halfx8 f;
            f[0]=(half_t)a[0]; f[1]=(half_t)a[1]; f[2]=(half_t)a[2]; f[3]=(half_t)a[3];
            f[4]=(half_t)c2[0];f[5]=(half_t)c2[1];f[6]=(half_t)c2[2];f[7]=(half_t)c2[3];
            wa[m][cc] = f;
        }
    }

    __syncthreads();

    #pragma unroll
    for (int m = 0; m < 3; ++m) {
        f32x4 acc[4] = {};
        #pragma unroll
        for (int tt = 0; tt < 4; ++tt) {
            #pragma unroll
            for (int cc = 0; cc < 4; ++cc) {
                halfx8 bfrag = *(const halfx8*)&xt[tt * 16 + rowA][cc * 32 + kgrp * 8];
                acc[tt] = __builtin_amdgcn_mfma_f32_16x16x32_f16(wa[m][cc], bfrag, acc[tt], 0, 0, 0);
            }
        }
        float bias[4];
        #pragma unroll
        for (int r = 0; r < 4; ++r) bias[r] = Bs[m][h0 + row_d + r];

        if (m < 2) {
            const float sc = (m == 0) ? L2E : 1.0f;   // fold log2e into theta
            #pragma unroll
            for (int tt = 0; tt < 4; ++tt)
                #pragma unroll
                for (int r = 0; r < 4; ++r)
                    ts[tt * 16 + rowA][h0 + row_d + r] = (half_t)((acc[tt][r] + bias[r]) * sc);
            __syncthreads();
            half_t* dst = (m == 0 ? Q : Ko) + ((size_t)b * T_ + t0) * H_;
            #pragma unroll
            for (int it = 0; it < 2; ++it) {
                int q = it * 256 + tid;
                int t = q >> 3, hc = q & 7;
                *(halfx8*)(dst + (size_t)t * H_ + hc * 8) = *(const halfx8*)&ts[t][hc * 8];
            }
            __syncthreads();
        } else {
            half_t* dst = Vt + (size_t)b * H_ * T_ + t0;
            #pragma unroll
            for (int tt = 0; tt < 4; ++tt)
                #pragma unroll
                for (int r = 0; r < 4; ++r)
                    dst[(size_t)(h0 + row_d + r) * T_ + tt * 16 + rowA] = (half_t)(acc[tt][r] + bias[r]);
        }
    }
}

// ---------------------------------------------------------------------------
// Kernel 2: flash attention, swapped-operand form.
// Block: 4 waves x 16 q-rows = 64 q-rows; grid = B * T/64 = 512 (2 blocks/CU,
// 2 waves/SIMD for latency hiding). Per KV tile (64 s): St = mfma(K, Q) ->
// lane owns one q-col, 16 s-values => in-register softmax (2 shuffles),
// defer-max rescale (skip O/l rescale unless max grows > 8 in log2 domain).
// P packed via cvt_pkrtz -> wave-private LDS -> PV as O^T = mfma(V^T, P^T).
// K/V double-buffered in LDS with register prefetch (one barrier per tile).
// ---------------------------------------------------------------------------
__global__ __launch_bounds__(256) void attn_kernel(
    const half_t* __restrict__ Q, const half_t* __restrict__ K,
    const half_t* __restrict__ Vt, half_t* __restrict__ O)
{
    __shared__ __align__(16) half_t Kt[2][64][72];   // [buf][s][h]
    __shared__ __align__(16) half_t Vl[2][64][72];   // [buf][d][s]
    __shared__ __align__(16) half_t Pl[4][16][72];   // [wave][q][s]

    const int tid  = threadIdx.x;
    const int lane = tid & 63;
    const int wave = tid >> 6;
    const int b    = blockIdx.x >> 6;
    const int t0   = (blockIdx.x & 63) << 6;   // 64 q-rows per block
    const int rowA = lane & 15;
    const int kgrp = lane >> 4;

    const int q0 = t0 + wave * 16;

    // Q fragments for this wave's 16 rows (B-operand layout == A layout)
    const half_t* qr = Q + ((size_t)b * T_ + q0 + rowA) * H_ + kgrp * 8;
    halfx8 qf[2];
    qf[0] = *(const halfx8*)qr;
    qf[1] = *(const halfx8*)(qr + 32);

    f32x4 oacc[4] = {};                   // [dt] : O^T[d][q]
    float mr = -INFINITY, lr = 0.f;

    // staging: each thread owns 2 x 16B chunks of K and of V per tile
    const int r0 = tid >> 3;     // 0..31 (+32 for second chunk)
    const int c8 = (tid & 7) * 8;
    const half_t* kp = K  + (size_t)b * T_ * H_ + (size_t)r0 * H_ + c8;
    const half_t* vp = Vt + (size_t)b * H_ * T_ + (size_t)r0 * T_ + c8;

    halfx8 rK0, rK1, rV0, rV1;
    rK0 = *(const halfx8*)(kp);
    rK1 = *(const halfx8*)(kp + 32 * H_);
    rV0 = *(const halfx8*)(vp);
    rV1 = *(const halfx8*)(vp + 32 * T_);
    kp += 64 * H_; vp += 64;

    *(halfx8*)&Kt[0][r0][c8]      = rK0;
    *(halfx8*)&Kt[0][r0 + 32][c8] = rK1;
    *(halfx8*)&Vl[0][r0][c8]      = rV0;
    *(halfx8*)&Vl[0][r0 + 32][c8] = rV1;
    __syncthreads();

    for (int t = 0; t < T_ / 64; ++t) {
        const int cur = t & 1;
        const bool more = (t + 1 < T_ / 64);
        if (more) {   // issue next-tile loads; land under compute
            rK0 = *(const halfx8*)(kp);
            rK1 = *(const halfx8*)(kp + 32 * H_);
            rV0 = *(const halfx8*)(vp);
            rV1 = *(const halfx8*)(vp + 32 * T_);
            kp += 64 * H_; vp += 64;
        }

        // ---- St = K_tile . Q^T  (D: col=q, row=s) ----
        f32x4 sacc[4] = {};
        __builtin_amdgcn_s_setprio(1);
        #pragma unroll
        for (int st = 0; st < 4; ++st) {
            #pragma unroll
            for (int hc = 0; hc < 2; ++hc) {
                halfx8 kf = *(const halfx8*)&Kt[cur][st * 16 + rowA][hc * 32 + kgrp * 8];
                sacc[st] = __builtin_amdgcn_mfma_f32_16x16x32_f16(kf, qf[hc], sacc[st], 0, 0, 0);
            }
        }
        __builtin_amdgcn_s_setprio(0);

        // ---- in-register online softmax (scores already in log2 domain) ----
        float pm = sacc[0][0];
        #pragma unroll
        for (int st = 0; st < 4; ++st)
            #pragma unroll
            for (int r = 0; r < 4; ++r)
                pm = fmaxf(pm, sacc[st][r]);
        pm = fmaxf(pm, __shfl_xor(pm, 16));
        pm = fmaxf(pm, __shfl_xor(pm, 32));
        // defer-max: only rescale when the max grew materially (log2 domain)
        if (__any(pm > mr + 8.f)) {
            float mnew  = fmaxf(mr, pm);
            float scale = exp2f(mr - mnew);
            mr = mnew;
            lr *= scale;
            #pragma unroll
            for (int dt = 0; dt < 4; ++dt) oacc[dt] *= scale;
        }
        f32x4 ps4 = {0.f, 0.f, 0.f, 0.f};
        #pragma unroll
        for (int st = 0; st < 4; ++st) {
            #pragma unroll
            for (int r = 0; r < 4; ++r)
                sacc[st][r] = exp2f(sacc[st][r] - mr);
            ps4 += sacc[st];
        }
        float ps = (ps4[0] + ps4[1]) + (ps4[2] + ps4[3]);
        ps += __shfl_xor(ps, 16);
        ps += __shfl_xor(ps, 32);
        lr += ps;
        // pack P^T and write wave-private (vectorized 8B, q-major)
        #pragma unroll
        for (int st = 0; st < 4; ++st) {
            union { halfx2 h2[2]; halfx4 h4; } u;
            u.h2[0] = pk2(sacc[st][0], sacc[st][1]);
            u.h2[1] = pk2(sacc[st][2], sacc[st][3]);
            *(halfx4*)&Pl[wave][rowA][st * 16 + kgrp * 4] = u.h4;
        }

        // ---- O^T += V^T . P^T ----
        __builtin_amdgcn_s_setprio(1);
        #pragma unroll
        for (int sc2 = 0; sc2 < 2; ++sc2) {
            halfx8 pf = *(const halfx8*)&Pl[wave][rowA][sc2 * 32 + kgrp * 8];
            #pragma unroll
            for (int dt = 0; dt < 4; ++dt) {
                halfx8 vf = *(const halfx8*)&Vl[cur][dt * 16 + rowA][sc2 * 32 + kgrp * 8];
                oacc[dt] = __builtin_amdgcn_mfma_f32_16x16x32_f16(vf, pf, oacc[dt], 0, 0, 0);
            }
        }
        __builtin_amdgcn_s_setprio(0);

        if (more) {   // write next tile into other buffer; single barrier
            const int nxt = cur ^ 1;
            *(halfx8*)&Kt[nxt][r0][c8]      = rK0;
            *(halfx8*)&Kt[nxt][r0 + 32][c8] = rK1;
            *(halfx8*)&Vl[nxt][r0][c8]      = rV0;
            *(halfx8*)&Vl[nxt][r0 + 32][c8] = rV1;
            __syncthreads();
        }
    }

    // ---- normalize + write O [B,T,H] (8B packed stores) ----
    float inv = 1.f / lr;
    half_t* orow = O + ((size_t)b * T_ + q0 + rowA) * H_;
    #pragma unroll
    for (int dt = 0; dt < 4; ++dt) {
        union { halfx2 h2[2]; halfx4 h4; } u;
        u.h2[0] = pk2(oacc[dt][0] * inv, oacc[dt][1] * inv);
        u.h2[1] = pk2(oacc[dt][2] * inv, oacc[dt][3] * inv);
        *(halfx4*)(orow + dt * 16 + kgrp * 4) = u.h4;
    }
}

// ---------------------------------------------------------------------------
// Kernel 3: out = x + b_out + w_out[128,64] @ O^T
// ---------------------------------------------------------------------------
__global__ __launch_bounds__(256) void outproj_kernel(
    const half_t* __restrict__ O, const float* __restrict__ w_out,
    const float* __restrict__ b_out, const float* __restrict__ x,
    float* __restrict__ out)
{
    __shared__ __align__(16) half_t Ot[64][72];   // [t][h]

    const int tid  = threadIdx.x;
    const int lane = tid & 63;
    const int wave = tid >> 6;
    const int b    = blockIdx.x >> 6;
    const int t0   = (blockIdx.x & 63) << 6;

    const int rowA  = lane & 15;
    const int kgrp  = lane >> 4;
    const int row_d = kgrp << 2;

    #pragma unroll
    for (int it = 0; it < 2; ++it) {
        int q = it * 256 + tid;
        int t = q >> 3, hc = q & 7;
        *(halfx8*)&Ot[t][hc * 8] = *(const halfx8*)(O + ((size_t)b * T_ + t0 + t) * H_ + hc * 8);
    }

    const int c0 = wave * 32;
    halfx8 wf[2][2];
    #pragma unroll
    for (int ct = 0; ct < 2; ++ct) {
        const float* wrow = w_out + (size_t)(c0 + ct * 16 + rowA) * H_;
        #pragma unroll
        for (int hc = 0; hc < 2; ++hc) {
            const float* p = wrow + hc * 32 + kgrp * 8;
            f32x4 a = *(const f32x4*)p;
            f32x4 c2 = *(const f32x4*)(p + 4);
            halfx8 f;
            f[0]=(half_t)a[0]; f[1]=(half_t)a[1]; f[2]=(half_t)a[2]; f[3]=(half_t)a[3];
            f[4]=(half_t)c2[0];f[5]=(half_t)c2[1];f[6]=(half_t)c2[2];f[7]=(half_t)c2[3];
            wf[ct][hc] = f;
        }
    }

    __syncthreads();

    #pragma unroll
    for (int ct = 0; ct < 2; ++ct) {
        #pragma unroll
        for (int tt = 0; tt < 4; ++tt) {
            f32x4 acc = {};
            #pragma unroll
            for (int hc = 0; hc < 2; ++hc) {
                halfx8 of = *(const halfx8*)&Ot[tt * 16 + rowA][hc * 32 + kgrp * 8];
                acc = __builtin_amdgcn_mfma_f32_16x16x32_f16(wf[ct][hc], of, acc, 0, 0, 0);
            }
            const int c = c0 + ct * 16 + row_d;
            const size_t base = (size_t)b * C_ * T_ + t0 + tt * 16 + rowA;
            #pragma unroll
            for (int r = 0; r < 4; ++r) {
                size_t idx = base + (size_t)(c + r) * T_;
                out[idx] = x[idx] + b_out[c + r] + acc[r];
            }
        }
    }
}

// ---------------------------------------------------------------------------
extern "C" void kernel_launch(void* const* d_in, const int* in_sizes, int n_in,
                              void* d_out, int out_size, void* d_ws, size_t ws_size,
                              hipStream_t stream) {
    const float* x       = (const float*)d_in[0];
    const float* w_theta = (const float*)d_in[1];
    const float* b_theta = (const float*)d_in[2];
    const float* w_phi   = (const float*)d_in[3];
    const float* b_phi   = (const float*)d_in[4];
    const float* w_g     = (const float*)d_in[5];
    const float* b_g     = (const float*)d_in[6];
    const float* w_out   = (const float*)d_in[7];
    const float* b_out   = (const float*)d_in[8];
    float* out = (float*)d_out;

    const size_t mat = (size_t)B_ * T_ * H_;   // 2 M elements
    half_t* Qw = (half_t*)d_ws;
    half_t* Kw = Qw + mat;
    half_t* Vw = Kw + mat;
    half_t* Ow = Vw + mat;                     // 16 MB of ws total

    proj_kernel<<<dim3(B_ * (T_ / 64)), dim3(256), 0, stream>>>(
        x, w_theta, b_theta, w_phi, b_phi, w_g, b_g, Qw, Kw, Vw);
    attn_kernel<<<dim3(B_ * (T_ / 64)), dim3(256), 0, stream>>>(Qw, Kw, Vw, Ow);
    outproj_kernel<<<dim3(B_ * (T_ / 64)), dim3(256), 0, stream>>>(Ow, w_out, b_out, x, out);
}

// Round 8
// 89.614 us; speedup vs baseline: 1.9285x; 1.2454x over previous
//
#include <hip/hip_runtime.h>
#include <hip/hip_bf16.h>

typedef _Float16 half_t;
typedef half_t halfx8 __attribute__((ext_vector_type(8)));
typedef half_t halfx4 __attribute__((ext_vector_type(4)));
typedef half_t halfx2 __attribute__((ext_vector_type(2)));
typedef __fp16 fp16x2 __attribute__((ext_vector_type(2)));
typedef float f32x4 __attribute__((ext_vector_type(4)));
typedef float f32x16 __attribute__((ext_vector_type(16)));
typedef int i32x4 __attribute__((ext_vector_type(4)));

#define B_ 8
#define C_ 128
#define T_ 4096
#define H_ 64
#define L2E 1.44269504088896340736f

static __device__ __forceinline__ halfx2 pk2(float a, float b) {
    fp16x2 r = __builtin_amdgcn_cvt_pkrtz(a, b);
    return __builtin_bit_cast(halfx2, r);
}
static __device__ __forceinline__ int pk2i(float a, float b) {
    return __builtin_bit_cast(int, __builtin_amdgcn_cvt_pkrtz(a, b));
}
// XOR-swizzle for 64-col (128B-row) LDS tiles; col in halves, multiple of 8
static __device__ __forceinline__ int swz(int row, int col) {
    return (row << 6) + (col ^ ((row & 7) << 3));
}

// ---------------------------------------------------------------------------
// Kernel 1: projections. theta/phi/g = W[64,128] @ x[b][128, t-tile(64)] + bias
// Q (theta, pre-scaled by log2e) [B,T,H], K (phi) [B,T,H], Vt (g) [B,H,T], f16
// ---------------------------------------------------------------------------
__global__ __launch_bounds__(256) void proj_kernel(
    const float* __restrict__ x,
    const float* __restrict__ w_theta, const float* __restrict__ b_theta,
    const float* __restrict__ w_phi,   const float* __restrict__ b_phi,
    const float* __restrict__ w_g,     const float* __restrict__ b_g,
    half_t* __restrict__ Q, half_t* __restrict__ Ko, half_t* __restrict__ Vt)
{
    __shared__ __align__(16) half_t xt[64][136];   // [t][c]
    __shared__ __align__(16) half_t ts[64][72];    // transpose buf [t][h]

    const int tid  = threadIdx.x;
    const int lane = tid & 63;
    const int wave = tid >> 6;
    const int b    = blockIdx.x >> 6;
    const int t0   = (blockIdx.x & 63) << 6;

    const int rowA  = lane & 15;
    const int kgrp  = lane >> 4;
    const int row_d = kgrp << 2;

    const float* xb = x + (size_t)b * C_ * T_ + t0;
    #pragma unroll
    for (int it = 0; it < 8; ++it) {
        int li = it * 256 + tid;
        int c  = li >> 4;
        int tc = li & 15;
        f32x4 v = *(const f32x4*)(xb + (size_t)c * T_ + tc * 4);
        #pragma unroll
        for (int j = 0; j < 4; ++j) xt[tc * 4 + j][c] = (half_t)v[j];
    }

    const int h0 = wave << 4;
    const float* Ws[3] = {w_theta, w_phi, w_g};
    const float* Bs[3] = {b_theta, b_phi, b_g};
    halfx8 wa[3][4];
    #pragma unroll
    for (int m = 0; m < 3; ++m) {
        const float* wrow = Ws[m] + (size_t)(h0 + rowA) * C_;
        #pragma unroll
        for (int cc = 0; cc < 4; ++cc) {
            const float* p = wrow + cc * 32 + kgrp * 8;
            f32x4 a = *(const f32x4*)p;
            f32x4 c2 = *(const f32x4*)(p + 4);
            halfx8 f;
            f[0]=(half_t)a[0]; f[1]=(half_t)a[1]; f[2]=(half_t)a[2]; f[3]=(half_t)a[3];
            f[4]=(half_t)c2[0];f[5]=(half_t)c2[1];f[6]=(half_t)c2[2];f[7]=(half_t)c2[3];
            wa[m][cc] = f;
        }
    }

    __syncthreads();

    #pragma unroll
    for (int m = 0; m < 3; ++m) {
        f32x4 acc[4] = {};
        #pragma unroll
        for (int tt = 0; tt < 4; ++tt) {
            #pragma unroll
            for (int cc = 0; cc < 4; ++cc) {
                halfx8 bfrag = *(const halfx8*)&xt[tt * 16 + rowA][cc * 32 + kgrp * 8];
                acc[tt] = __builtin_amdgcn_mfma_f32_16x16x32_f16(wa[m][cc], bfrag, acc[tt], 0, 0, 0);
            }
        }
        float bias[4];
        #pragma unroll
        for (int r = 0; r < 4; ++r) bias[r] = Bs[m][h0 + row_d + r];

        if (m < 2) {
            const float sc = (m == 0) ? L2E : 1.0f;   // fold log2e into theta
            #pragma unroll
            for (int tt = 0; tt < 4; ++tt)
                #pragma unroll
                for (int r = 0; r < 4; ++r)
                    ts[tt * 16 + rowA][h0 + row_d + r] = (half_t)((acc[tt][r] + bias[r]) * sc);
            __syncthreads();
            half_t* dst = (m == 0 ? Q : Ko) + ((size_t)b * T_ + t0) * H_;
            #pragma unroll
            for (int it = 0; it < 2; ++it) {
                int q = it * 256 + tid;
                int t = q >> 3, hc = q & 7;
                *(halfx8*)(dst + (size_t)t * H_ + hc * 8) = *(const halfx8*)&ts[t][hc * 8];
            }
            __syncthreads();
        } else {
            half_t* dst = Vt + (size_t)b * H_ * T_ + t0;
            #pragma unroll
            for (int tt = 0; tt < 4; ++tt)
                #pragma unroll
                for (int r = 0; r < 4; ++r)
                    dst[(size_t)(h0 + row_d + r) * T_ + tt * 16 + rowA] = (half_t)(acc[tt][r] + bias[r]);
        }
    }
}

// ---------------------------------------------------------------------------
// Kernel 2: flash attention, 32x32 MFMA swapped-operand + KV-split.
// Cross-lane (lane <-> lane+32) exchanges use __shfl_xor(,32) ONLY — its
// semantics are symmetric/direction-free (permlane32_swap direction was the
// R6/R7 failure). S^T = mfma_32x32x16(K,Q): lane owns q-col lane&31 and 16
// s-values per 32-tile; softmax in registers; P^T PV B-operand built
// in-register via cvt_pkrtz + one shfl pair per 16-k chunk.
// K/V in XOR-swizzled LDS, double-buffered, register prefetch, one barrier
// per tile. Output: per-split normalized O (f16) + m,l for merge.
// ---------------------------------------------------------------------------
__global__ __launch_bounds__(256, 4) void attn_kernel(
    const half_t* __restrict__ Q, const half_t* __restrict__ K,
    const half_t* __restrict__ Vt, half_t* __restrict__ Op,
    float* __restrict__ Mp, float* __restrict__ Lp, int NS)
{
    __shared__ __align__(16) half_t Ks[2][64 * 64];   // swizzled [s][h]
    __shared__ __align__(16) half_t Vs[2][64 * 64];   // swizzled [d][s]

    const int tid  = threadIdx.x;
    const int wave = tid >> 6;
    const int lane = tid & 63;
    const int qb   = blockIdx.x / NS;
    const int sp   = blockIdx.x - qb * NS;
    const int b    = qb >> 5;
    const int t0   = (qb & 31) << 7;       // 128 q-rows per block
    const int q0   = t0 + wave * 32;
    const int lq   = lane & 31;
    const int hi   = lane >> 5;
    const int NT   = T_ / (64 * NS);
    const int sbase = sp * (T_ / NS);

    // Q B-fragments (col=q, k=h): qf[kc][e] = Q[q0+lq][kc*16 + hi*8 + e]
    halfx8 qf[4];
    const half_t* qr = Q + ((size_t)b * T_ + q0 + lq) * H_ + hi * 8;
    #pragma unroll
    for (int kc = 0; kc < 4; ++kc) qf[kc] = *(const halfx8*)(qr + kc * 16);

    f32x16 oacc[2] = {};                    // O^T [2 d-tiles of 32][q]
    float mr = -INFINITY, lr = 0.f;

    // staging: thread owns 2 x 16B chunks of K and of V per tile
    const int r0 = tid >> 3;
    const int c8 = (tid & 7) * 8;
    const half_t* kp = K  + (size_t)b * T_ * H_ + (size_t)(sbase + r0) * H_ + c8;
    const half_t* vp = Vt + (size_t)b * H_ * T_ + (size_t)r0 * T_ + sbase + c8;

    halfx8 rK0 = *(const halfx8*)kp;
    halfx8 rK1 = *(const halfx8*)(kp + 32 * H_);
    halfx8 rV0 = *(const halfx8*)vp;
    halfx8 rV1 = *(const halfx8*)(vp + 32 * T_);
    kp += 64 * H_; vp += 64;

    *(halfx8*)&Ks[0][swz(r0, c8)]      = rK0;
    *(halfx8*)&Ks[0][swz(r0 + 32, c8)] = rK1;
    *(halfx8*)&Vs[0][swz(r0, c8)]      = rV0;
    *(halfx8*)&Vs[0][swz(r0 + 32, c8)] = rV1;
    __syncthreads();

    for (int t = 0; t < NT; ++t) {
        const int cur = t & 1;
        const bool more = (t + 1 < NT);
        if (more) {
            rK0 = *(const halfx8*)kp;
            rK1 = *(const halfx8*)(kp + 32 * H_);
            rV0 = *(const halfx8*)vp;
            rV1 = *(const halfx8*)(vp + 32 * T_);
            kp += 64 * H_; vp += 64;
        }

        // ---- S^T = K . Q^T : 2 s-tiles of 32, K-dim 64 = 4 chunks ----
        f32x16 sacc[2] = {};
        __builtin_amdgcn_s_setprio(1);
        #pragma unroll
        for (int st = 0; st < 2; ++st)
            #pragma unroll
            for (int kc = 0; kc < 4; ++kc) {
                halfx8 kf = *(const halfx8*)&Ks[cur][swz(st * 32 + lq, kc * 16 + hi * 8)];
                sacc[st] = __builtin_amdgcn_mfma_f32_32x32x16_f16(kf, qf[kc], sacc[st], 0, 0, 0);
            }
        __builtin_amdgcn_s_setprio(0);

        // ---- in-register online softmax (log2 domain) ----
        float pm = sacc[0][0];
        #pragma unroll
        for (int st = 0; st < 2; ++st)
            #pragma unroll
            for (int r = 0; r < 16; ++r)
                pm = fmaxf(pm, sacc[st][r]);
        pm = fmaxf(pm, __shfl_xor(pm, 32));   // combine lane<->lane+32
        if (__any(pm > mr + 8.f)) {           // defer-max rescale
            float mnew  = fmaxf(mr, pm);
            float scale = exp2f(mr - mnew);
            mr = mnew; lr *= scale;
            #pragma unroll
            for (int dt = 0; dt < 2; ++dt)
                #pragma unroll
                for (int r = 0; r < 16; ++r) oacc[dt][r] *= scale;
        }
        float ps = 0.f;
        #pragma unroll
        for (int st = 0; st < 2; ++st)
            #pragma unroll
            for (int r = 0; r < 16; ++r) {
                float p = exp2f(sacc[st][r] - mr);
                sacc[st][r] = p;
                ps += p;
            }
        lr += ps + __shfl_xor(ps, 32);

        // ---- build P^T B-fragments in-register ----
        // D-layout: lane(lq,hi) holds s_loc = (r&3) + 8*(r>>2) + 4*hi.
        // pfrag[sc] needs k = sc*16 + hi*8 + e. Per sc: own low words
        // (d0,d1), own high words (e0,e1); hi=0 needs partner d's, hi=1
        // needs partner e's -> one shfl pair, symmetric (direction-free).
        halfx8 pfrag[4];
        #pragma unroll
        for (int sc = 0; sc < 4; ++sc) {
            const int st = sc >> 1, rb = (sc & 1) * 8;
            int d0 = pk2i(sacc[st][rb + 0], sacc[st][rb + 1]);
            int d1 = pk2i(sacc[st][rb + 2], sacc[st][rb + 3]);
            int e0 = pk2i(sacc[st][rb + 4], sacc[st][rb + 5]);
            int e1 = pk2i(sacc[st][rb + 6], sacc[st][rb + 7]);
            int s0 = hi ? d0 : e0;
            int s1 = hi ? d1 : e1;
            int g0 = __shfl_xor(s0, 32);
            int g1 = __shfl_xor(s1, 32);
            i32x4 w;
            w[0] = hi ? g0 : d0;
            w[1] = hi ? g1 : d1;
            w[2] = hi ? e0 : g0;
            w[3] = hi ? e1 : g1;
            pfrag[sc] = __builtin_bit_cast(halfx8, w);
        }

        // ---- O^T += V^T . P^T : 2 d-tiles x 4 s-chunks ----
        __builtin_amdgcn_s_setprio(1);
        #pragma unroll
        for (int dt = 0; dt < 2; ++dt)
            #pragma unroll
            for (int sc = 0; sc < 4; ++sc) {
                halfx8 vf = *(const halfx8*)&Vs[cur][swz(dt * 32 + lq, sc * 16 + hi * 8)];
                oacc[dt] = __builtin_amdgcn_mfma_f32_32x32x16_f16(vf, pfrag[sc], oacc[dt], 0, 0, 0);
            }
        __builtin_amdgcn_s_setprio(0);

        if (more) {
            const int nxt = cur ^ 1;
            *(halfx8*)&Ks[nxt][swz(r0, c8)]      = rK0;
            *(halfx8*)&Ks[nxt][swz(r0 + 32, c8)] = rK1;
            *(halfx8*)&Vs[nxt][swz(r0, c8)]      = rV0;
            *(halfx8*)&Vs[nxt][swz(r0 + 32, c8)] = rV1;
            __syncthreads();
        }
    }

    // ---- epilogue: normalized partial O (f16) + m,l ----
    const int BT = B_ * T_;
    const int grow = b * T_ + q0 + lq;
    float inv = 1.f / lr;
    half_t* od = Op + ((size_t)sp * BT + grow) * H_;
    #pragma unroll
    for (int dt = 0; dt < 2; ++dt)
        #pragma unroll
        for (int g = 0; g < 4; ++g) {
            union { halfx2 h2[2]; halfx4 h4; } u;
            u.h2[0] = pk2(oacc[dt][g * 4 + 0] * inv, oacc[dt][g * 4 + 1] * inv);
            u.h2[1] = pk2(oacc[dt][g * 4 + 2] * inv, oacc[dt][g * 4 + 3] * inv);
            *(halfx4*)(od + dt * 32 + g * 8 + hi * 4) = u.h4;
        }
    if (Mp != nullptr && hi == 0) {
        Mp[(size_t)sp * BT + grow] = mr;
        Lp[(size_t)sp * BT + grow] = lr;
    }
}

// ---------------------------------------------------------------------------
// Kernel 2b: merge KV-split partials. O = sum_i w_i O_i / sum_i w_i,
// w_i = l_i * 2^(m_i - m*). Thread handles 8 h of one q-row.
// ---------------------------------------------------------------------------
__global__ __launch_bounds__(256) void merge_kernel(
    const half_t* __restrict__ Op, const float* __restrict__ Mp,
    const float* __restrict__ Lp, half_t* __restrict__ O, int NS)
{
    const int idx = blockIdx.x * 256 + threadIdx.x;
    const int row = idx >> 3;
    const int hc  = (idx & 7) * 8;
    const int BT  = B_ * T_;

    float m = -INFINITY;
    for (int s = 0; s < NS; ++s) m = fmaxf(m, Mp[(size_t)s * BT + row]);
    float W = 0.f;
    float acc[8] = {};
    for (int s = 0; s < NS; ++s) {
        float w = Lp[(size_t)s * BT + row] * exp2f(Mp[(size_t)s * BT + row] - m);
        W += w;
        halfx8 o = *(const halfx8*)(Op + ((size_t)s * BT + row) * H_ + hc);
        #pragma unroll
        for (int j = 0; j < 8; ++j) acc[j] += w * (float)o[j];
    }
    float inv = 1.f / W;
    halfx8 r;
    #pragma unroll
    for (int j = 0; j < 8; ++j) r[j] = (half_t)(acc[j] * inv);
    *(halfx8*)(O + (size_t)row * H_ + hc) = r;
}

// ---------------------------------------------------------------------------
// Kernel 3: out = x + b_out + w_out[128,64] @ O^T
// ---------------------------------------------------------------------------
__global__ __launch_bounds__(256) void outproj_kernel(
    const half_t* __restrict__ O, const float* __restrict__ w_out,
    const float* __restrict__ b_out, const float* __restrict__ x,
    float* __restrict__ out)
{
    __shared__ __align__(16) half_t Ot[64][72];   // [t][h]

    const int tid  = threadIdx.x;
    const int lane = tid & 63;
    const int wave = tid >> 6;
    const int b    = blockIdx.x >> 6;
    const int t0   = (blockIdx.x & 63) << 6;

    const int rowA  = lane & 15;
    const int kgrp  = lane >> 4;
    const int row_d = kgrp << 2;

    #pragma unroll
    for (int it = 0; it < 2; ++it) {
        int q = it * 256 + tid;
        int t = q >> 3, hc = q & 7;
        *(halfx8*)&Ot[t][hc * 8] = *(const halfx8*)(O + ((size_t)b * T_ + t0 + t) * H_ + hc * 8);
    }

    const int c0 = wave * 32;
    halfx8 wf[2][2];
    #pragma unroll
    for (int ct = 0; ct < 2; ++ct) {
        const float* wrow = w_out + (size_t)(c0 + ct * 16 + rowA) * H_;
        #pragma unroll
        for (int hc = 0; hc < 2; ++hc) {
            const float* p = wrow + hc * 32 + kgrp * 8;
            f32x4 a = *(const f32x4*)p;
            f32x4 c2 = *(const f32x4*)(p + 4);
            halfx8 f;
            f[0]=(half_t)a[0]; f[1]=(half_t)a[1]; f[2]=(half_t)a[2]; f[3]=(half_t)a[3];
            f[4]=(half_t)c2[0];f[5]=(half_t)c2[1];f[6]=(half_t)c2[2];f[7]=(half_t)c2[3];
            wf[ct][hc] = f;
        }
    }

    __syncthreads();

    #pragma unroll
    for (int ct = 0; ct < 2; ++ct) {
        #pragma unroll
        for (int tt = 0; tt < 4; ++tt) {
            f32x4 acc = {};
            #pragma unroll
            for (int hc = 0; hc < 2; ++hc) {
                halfx8 of = *(const halfx8*)&Ot[tt * 16 + rowA][hc * 32 + kgrp * 8];
                acc = __builtin_amdgcn_mfma_f32_16x16x32_f16(wf[ct][hc], of, acc, 0, 0, 0);
            }
            const int c = c0 + ct * 16 + row_d;
            const size_t base = (size_t)b * C_ * T_ + t0 + tt * 16 + rowA;
            #pragma unroll
            for (int r = 0; r < 4; ++r) {
                size_t idx = base + (size_t)(c + r) * T_;
                out[idx] = x[idx] + b_out[c + r] + acc[r];
            }
        }
    }
}

// ---------------------------------------------------------------------------
extern "C" void kernel_launch(void* const* d_in, const int* in_sizes, int n_in,
                              void* d_out, int out_size, void* d_ws, size_t ws_size,
                              hipStream_t stream) {
    const float* x       = (const float*)d_in[0];
    const float* w_theta = (const float*)d_in[1];
    const float* b_theta = (const float*)d_in[2];
    const float* w_phi   = (const float*)d_in[3];
    const float* b_phi   = (const float*)d_in[4];
    const float* w_g     = (const float*)d_in[5];
    const float* b_g     = (const float*)d_in[6];
    const float* w_out   = (const float*)d_in[7];
    const float* b_out   = (const float*)d_in[8];
    float* out = (float*)d_out;

    const size_t mat = (size_t)B_ * T_ * H_;   // 2 M elements
    const size_t BT  = (size_t)B_ * T_;        // 32768 rows
    half_t* Qw = (half_t*)d_ws;
    half_t* Kw = Qw + mat;
    half_t* Vw = Kw + mat;
    half_t* Ow = Vw + mat;                     // base: 16 MB
    const size_t base_b = 4 * mat * sizeof(half_t);

    auto need = [&](size_t ns) { return base_b + ns * mat * 2 + ns * BT * 8; };
    const int NS = (ws_size >= need(4)) ? 4 : ((ws_size >= need(2)) ? 2 : 1);

    half_t* Opart = Ow;
    float*  Mp = nullptr;
    float*  Lp = nullptr;
    if (NS > 1) {
        Opart = (half_t*)((char*)d_ws + base_b);
        Mp = (float*)((char*)d_ws + base_b + (size_t)NS * mat * 2);
        Lp = Mp + (size_t)NS * BT;
    }

    proj_kernel<<<dim3(B_ * (T_ / 64)), dim3(256), 0, stream>>>(
        x, w_theta, b_theta, w_phi, b_phi, w_g, b_g, Qw, Kw, Vw);
    attn_kernel<<<dim3(B_ * (T_ / 128) * NS), dim3(256), 0, stream>>>(
        Qw, Kw, Vw, Opart, Mp, Lp, NS);
    if (NS > 1)
        merge_kernel<<<dim3((int)(BT * H_ / (256 * 8))), dim3(256), 0, stream>>>(
            Opart, Mp, Lp, Ow, NS);
    outproj_kernel<<<dim3(B_ * (T_ / 64)), dim3(256), 0, stream>>>(Ow, w_out, b_out, x, out);
}